// Round 7
// baseline (430.415 us; speedup 1.0000x reference)
//
#include <hip/hip_runtime.h>

typedef unsigned short u16;
typedef unsigned long long u64;
typedef __attribute__((ext_vector_type(8))) short bf16x8;
typedef __attribute__((ext_vector_type(4))) float f32x4;

// B=4, S=2048, D=1024, H=16, HD=64, M=B*S=8192
#define C_SCALE 0.18033688011112043f   // 0.125 * log2(e), folded into Q

__device__ __forceinline__ u16 f2b(float x) {
  union { float f; unsigned u; } c; c.f = x;
  unsigned r = (c.u + 0x7fffu + ((c.u >> 16) & 1u)) >> 16;
  return (u16)r;
}

__device__ __forceinline__ unsigned pk2(float a, float b) {
#if __has_builtin(__builtin_amdgcn_cvt_pk_bf16_f32)
  typedef __attribute__((ext_vector_type(2))) __bf16 b2;
  b2 r = __builtin_amdgcn_cvt_pk_bf16_f32(a, b);
  union { b2 v; unsigned u; } c; c.v = r;
  return c.u;
#else
  union { float f; unsigned u; } x, y;
  x.f = a; y.f = b;
  return ((x.u + 0x8000u) >> 16) | ((y.u + 0x8000u) & 0xffff0000u);
#endif
}

__device__ __forceinline__ void gll16(const u16* g, u16* l) {
  __builtin_amdgcn_global_load_lds(
      (const __attribute__((address_space(1))) void*)g,
      (__attribute__((address_space(3))) void*)l, 16, 0, 0);
}

// exp2 over 8 scores, pack to bf16, blend with 1.0 under halfword select
// mask (0xFFFF keep / 0x0000 -> bf16 1.0). LLVM folds each line to v_bfi.
__device__ __forceinline__ bf16x8 pblend(f32x4 sa, f32x4 sb, int4 mw) {
  unsigned m0 = (unsigned)mw.x, m1 = (unsigned)mw.y;
  unsigned m2 = (unsigned)mw.z, m3 = (unsigned)mw.w;
  union { unsigned u[4]; bf16x8 v; } pu;
  pu.u[0] = (m0 & pk2(__builtin_amdgcn_exp2f(sa[0]),
                      __builtin_amdgcn_exp2f(sa[1]))) | (~m0 & 0x3f803f80u);
  pu.u[1] = (m1 & pk2(__builtin_amdgcn_exp2f(sa[2]),
                      __builtin_amdgcn_exp2f(sa[3]))) | (~m1 & 0x3f803f80u);
  pu.u[2] = (m2 & pk2(__builtin_amdgcn_exp2f(sb[0]),
                      __builtin_amdgcn_exp2f(sb[1]))) | (~m2 & 0x3f803f80u);
  pu.u[3] = (m3 & pk2(__builtin_amdgcn_exp2f(sb[2]),
                      __builtin_amdgcn_exp2f(sb[3]))) | (~m3 & 0x3f803f80u);
  return pu.v;
}

// ---------------------------------------------------------------------------
// fp32 -> bf16 for all three inputs in one dispatch. Grid (512, 3).
// ---------------------------------------------------------------------------
__global__ __launch_bounds__(256) void cvt_bf16_3(
    const float4* __restrict__ s0, const float4* __restrict__ s1,
    const float4* __restrict__ s2, ushort4* __restrict__ d0,
    ushort4* __restrict__ d1, ushort4* __restrict__ d2, int n4) {
  const int z = blockIdx.y;
  const float4* src = z == 0 ? s0 : z == 1 ? s1 : s2;
  ushort4* dst = z == 0 ? d0 : z == 1 ? d1 : d2;
  int stride = gridDim.x * 256;
  for (int i = blockIdx.x * 256 + threadIdx.x; i < n4; i += stride) {
    float4 v = src[i];
    ushort4 o = { f2b(v.x), f2b(v.y), f2b(v.z), f2b(v.w) };
    dst[i] = o;
  }
}

// ---------------------------------------------------------------------------
// All four weight transposes in one dispatch. Flat grid 1024 blocks.
// ---------------------------------------------------------------------------
__global__ __launch_bounds__(256) void transpose_cvt_all(
    const float* __restrict__ Wq, const float* __restrict__ Wk,
    const float* __restrict__ Wv, const float* __restrict__ Wo,
    u16* __restrict__ wq_t, u16* __restrict__ wk_t,
    u16* __restrict__ wv_t, u16* __restrict__ wo_t) {
  __shared__ u16 tile[64][65];
  const int id = blockIdx.x;
  const int which = id >> 8, sub = id & 255;
  const float* s;
  u16* d;
  int R, C, r0, c0;
  if (which < 3) {
    const float* W = which == 0 ? Wq : which == 1 ? Wk : Wv;
    u16* D = which == 0 ? wq_t : which == 1 ? wk_t : wv_t;
    int h = sub >> 4, rt = sub & 15;
    s = W + (size_t)h * 1024 * 64;
    d = D + (size_t)h * 64 * 1024;
    R = 1024; C = 64; r0 = rt * 64; c0 = 0;
  } else {
    s = Wo; d = wo_t;
    R = 1024; C = 1024; r0 = ((sub >> 4) & 15) * 64; c0 = (sub & 15) * 64;
  }
  const int t = threadIdx.x;
#pragma unroll
  for (int rep = 0; rep < 16; ++rep) {
    int idx = rep * 256 + t;
    int i = idx >> 6, j = idx & 63;
    tile[j][i] = f2b(s[(size_t)(r0 + i) * C + c0 + j]);
  }
  __syncthreads();
#pragma unroll
  for (int rep = 0; rep < 16; ++rep) {
    int idx = rep * 256 + t;
    int jj = idx >> 6, ii = idx & 63;
    d[(size_t)(c0 + jj) * R + r0 + ii] = tile[jj][ii];
  }
}

// ---------------------------------------------------------------------------
// Expand mask int32 [B,S,S] -> u16 halfword SELECT masks: 0xFFFF where
// mask!=0 (keep exp2(s)), 0x0000 where mask==0 (inject bf16 1.0 in attn).
// ---------------------------------------------------------------------------
__global__ __launch_bounds__(256) void expand_mask(
    const int4* __restrict__ m, ushort4* __restrict__ mb, int n4) {
  int stride = gridDim.x * 256;
  for (int i = blockIdx.x * 256 + threadIdx.x; i < n4; i += stride) {
    int4 v = m[i];
    ushort4 o = { (u16)(v.x ? 0xFFFF : 0), (u16)(v.y ? 0xFFFF : 0),
                  (u16)(v.z ? 0xFFFF : 0), (u16)(v.w ? 0xFFFF : 0) };
    mb[i] = o;
  }
}

// ---------------------------------------------------------------------------
// GEMM core: 128x128 tile, BK=64, global_load_lds width-16 staging.
// ---------------------------------------------------------------------------
__device__ __forceinline__ void gemm_core(
    const u16* __restrict__ A, const u16* __restrict__ W,
    u16* Asm, u16* Bsm, int s0, int n0, int wv, int lane,
    int m16, int q4, f32x4 acc[4][4]) {
  const int rsub = lane >> 3, csub = lane & 7;
  const int wr = (wv & 1) * 64, wc = (wv >> 1) * 64;
  for (int k0 = 0; k0 < 1024; k0 += 64) {
    __syncthreads();
#pragma unroll
    for (int i = 0; i < 4; ++i) {
      int chunk = wv * 4 + i;
      gll16(A + (size_t)(s0 + chunk * 8 + rsub) * 1024 + k0 + csub * 8,
            Asm + chunk * 512 + lane * 8);
      gll16(W + (size_t)(n0 + chunk * 8 + rsub) * 1024 + k0 + csub * 8,
            Bsm + chunk * 512 + lane * 8);
    }
    __syncthreads();
#pragma unroll
    for (int ks = 0; ks < 2; ++ks) {
      bf16x8 af[4], bfr[4];
#pragma unroll
      for (int i = 0; i < 4; ++i)
        af[i] = *(const bf16x8*)(Asm + (wr + i * 16 + m16) * 64 + ks * 32 + q4 * 8);
#pragma unroll
      for (int j = 0; j < 4; ++j)
        bfr[j] = *(const bf16x8*)(Bsm + (wc + j * 16 + m16) * 64 + ks * 32 + q4 * 8);
#pragma unroll
      for (int i = 0; i < 4; ++i)
#pragma unroll
        for (int j = 0; j < 4; ++j)
          acc[i][j] = __builtin_amdgcn_mfma_f32_16x16x32_bf16(af[i], bfr[j], acc[i][j], 0, 0, 0);
    }
  }
}

// ---------------------------------------------------------------------------
// Merged QKV projection: grid (64, 8, 3). z=0: Q (scaled), z=1: K, z=2: V
// (transposed epilogue -> vt[b][h][e][2048]). (256,3): 3 blocks/CU.
// ---------------------------------------------------------------------------
__global__ __launch_bounds__(256, 3) void qkv_gemm(
    const u16* __restrict__ xq, const u16* __restrict__ xk,
    const u16* __restrict__ xv, const u16* __restrict__ wq,
    const u16* __restrict__ wk, const u16* __restrict__ wv_,
    const float* __restrict__ bq, const float* __restrict__ bk,
    const float* __restrict__ bv, u16* __restrict__ qb,
    u16* __restrict__ kb, u16* __restrict__ vtb) {
  __shared__ u16 S[17408];
  u16* Asm = S;
  u16* Bsm = S + 8192;
  const int z = blockIdx.z;
  const u16* A = z == 0 ? xq : z == 1 ? xk : xv;
  const u16* W = z == 0 ? wq : z == 1 ? wk : wv_;
  const float* bias = z == 0 ? bq : z == 1 ? bk : bv;
  const int s0 = blockIdx.x * 128, n0 = blockIdx.y * 128;
  const int t = threadIdx.x, wvi = t >> 6, lane = t & 63;
  const int m16 = lane & 15, q4 = lane >> 4;
  const int wr = (wvi & 1) * 64, wc = (wvi >> 1) * 64;
  f32x4 acc[4][4];
#pragma unroll
  for (int i = 0; i < 4; ++i)
#pragma unroll
    for (int j = 0; j < 4; ++j) acc[i][j] = (f32x4){0.f, 0.f, 0.f, 0.f};

  gemm_core(A, W, Asm, Bsm, s0, n0, wvi, lane, m16, q4, acc);

  if (z < 2) {
    u16* out = z == 0 ? qb : kb;
    const float scale = z == 0 ? C_SCALE : 1.0f;
#pragma unroll
    for (int j = 0; j < 4; ++j) {
      int n = n0 + wc + j * 16 + m16;
      int h = n >> 6, e = n & 63;
      float bval = bias[n];
#pragma unroll
      for (int i = 0; i < 4; ++i)
#pragma unroll
        for (int r = 0; r < 4; ++r) {
          int s = s0 + wr + i * 16 + q4 * 4 + r;
          int bi = s >> 11, sl = s & 2047;
          out[((size_t)(bi * 16 + h) * 2048 + sl) * 64 + e] =
              f2b((acc[i][j][r] + bval) * scale);
        }
    }
  } else {
    // V: transpose through LDS (stride 136), write vt[b][h][e][2048]
    __syncthreads();
#pragma unroll
    for (int j = 0; j < 4; ++j) {
      int nl = wc + j * 16 + m16;
      float bval = bias[n0 + nl];
#pragma unroll
      for (int i = 0; i < 4; ++i)
#pragma unroll
        for (int r = 0; r < 4; ++r)
          S[nl * 136 + wr + i * 16 + q4 * 4 + r] = f2b(acc[i][j][r] + bval);
    }
    __syncthreads();
    const int bi = s0 >> 11, sl0 = s0 & 2047;
#pragma unroll
    for (int rep = 0; rep < 8; ++rep) {  // 128x128 tile = 2048 int4 units
      int u = rep * 256 + t;
      int rr = u >> 4, cc = (u & 15) * 8;
      int n = n0 + rr, h = n >> 6, e = n & 63;
      *(int4*)(vtb + ((size_t)(bi * 16 + h) * 64 + e) * 2048 + sl0 + cc) =
          *(const int4*)(S + rr * 136 + cc);
    }
  }
}

// ---------------------------------------------------------------------------
// Output GEMM: fp32 out [s][1024]. Grid (64, 8).
// ---------------------------------------------------------------------------
__global__ __launch_bounds__(256, 2) void out_gemm(
    const u16* __restrict__ Z, const u16* __restrict__ Wot,
    const float* __restrict__ bo, float* __restrict__ out) {
  __shared__ u16 S[17408];
  u16* Asm = S;
  u16* Bsm = S + 8192;
  const int s0 = blockIdx.x * 128, n0 = blockIdx.y * 128;
  const int t = threadIdx.x, wvi = t >> 6, lane = t & 63;
  const int m16 = lane & 15, q4 = lane >> 4;
  const int wr = (wvi & 1) * 64, wc = (wvi >> 1) * 64;
  f32x4 acc[4][4];
#pragma unroll
  for (int i = 0; i < 4; ++i)
#pragma unroll
    for (int j = 0; j < 4; ++j) acc[i][j] = (f32x4){0.f, 0.f, 0.f, 0.f};

  gemm_core(Z, Wot, Asm, Bsm, s0, n0, wvi, lane, m16, q4, acc);

#pragma unroll
  for (int j = 0; j < 4; ++j) {
    int n = n0 + wc + j * 16 + m16;
    float bval = bo[n];
#pragma unroll
    for (int i = 0; i < 4; ++i)
#pragma unroll
      for (int r = 0; r < 4; ++r) {
        int s = s0 + wr + i * 16 + q4 * 4 + r;
        out[(size_t)s * 1024 + n] = acc[i][j][r] + bval;
      }
  }
}

// ---------------------------------------------------------------------------
// Flash attention, no-max softmax.
// Masking: mk holds halfword select masks (0xFFFF keep / 0x0000 masked);
// pa = BFI(m, pk2(exp2(s)), 1.0bf16) -- bit-identical to exp2(s*m) with
// m in {1.0, 0.0}.
// Round-7 = round-4 EXACT structure + bound + BFI blend only.
//  - launch_bounds (512,4): forces <=64 VGPR. r6 proved the 64-VGPR
//    boundary IS the 2-blocks/CU residency step (VGPR 68 -> occupancy
//    37%->22%, dur 112.6->128.3). The cap is load-bearing; keep it.
//  - BFI blend (r5/r6 proven: VALUBusy 53->46%), register-neutral vs r4
//    (replaces blo/bhi+mul temps with pure bitwise on the same values).
//  - Single kt loop, runtime cur, cm/nm compile-time-indexed copies
//    (r4 proven spill-free at 64 VGPR). No setprio (r2 spill + m190 null).
//  - Tripwire: WRITE_SIZE >> 20 MB or VGPR > 64 => BFI needs 65+, keep r4.
// ---------------------------------------------------------------------------
__global__ __launch_bounds__(512, 4) void attn(
    const u16* __restrict__ qb, const u16* __restrict__ kb,
    const u16* __restrict__ vt, const u16* __restrict__ mk,
    u16* __restrict__ zb) {
  __shared__ u16 Kl[2][4096];  // permuted-key rows, [64][64] swizzled
  __shared__ u16 Vl[2][4096];  // [e][key] natural, swizzled
  const int id = blockIdx.x;
  const int qi = id >> 6;      // 0..7 (256-q tiles)
  const int bh = id & 63;
  const int b = bh >> 4, h = bh & 15;
  const int t = threadIdx.x, w = t >> 6, lane = t & 63;  // w 0..7
  const int m16 = lane & 15, q4 = lane >> 4;
  const size_t bho = (size_t)bh * 2048;
  const u16* qp = qb + bho * 64;
  const u16* kp = kb + bho * 64;
  const u16* vp = vt + bho * 64;  // [e][2048]
  const int qbase = qi * 256 + w * 32;

  bf16x8 qa[2][2];
#pragma unroll
  for (int qg = 0; qg < 2; ++qg)
#pragma unroll
    for (int ks = 0; ks < 2; ++ks)
      qa[qg][ks] = *(const bf16x8*)(qp + (size_t)(qbase + qg * 16 + m16) * 64 + ks * 32 + q4 * 8);

  f32x4 oacc[2][4], lacc[2];
#pragma unroll
  for (int qg = 0; qg < 2; ++qg) {
    lacc[qg] = (f32x4){0.f, 0.f, 0.f, 0.f};
#pragma unroll
    for (int g = 0; g < 4; ++g) oacc[qg][g] = (f32x4){0.f, 0.f, 0.f, 0.f};
  }
  bf16x8 ones;
#pragma unroll
  for (int j = 0; j < 8; ++j) ones[j] = (short)0x3f80;

  // select-mask rows for this lane's two q rows; keys contiguous
  const u16* mrow[2];
  mrow[0] = mk + ((size_t)b * 2048 + qbase + m16) * 2048;
  mrow[1] = mk + ((size_t)b * 2048 + qbase + 16 + m16) * 2048;

  const int ch = t & 7, rw = t >> 3;  // rw in 0..63
  const int r5 = rw & 31;
  const int sK = (rw & 32) + (((r5 >> 2) & 1) * 16) + (((r5 >> 3) & 3) * 4) + (r5 & 3);

  // XOR-swizzle terms (u16 units; 8 u16 = 16 B slot)
  const int kwc = (ch ^ (sK & 7)) * 8;       // K write col
  const int vwc = (ch ^ (rw & 7)) * 8;       // V write col (row = e = rw)
  const int sw = (m16 & 7) * 8;              // read-side XOR (row&7 == m16&7)
  const int rcol0 = (q4 * 8) ^ sw;           // ks=0 / bb=0 read col
  const int rcol1 = (32 + q4 * 8) ^ sw;      // ks=1 / bb=1 read col

  // prefetch tile 0 + mask 0
  int4 pk0 = *(const int4*)(kp + (size_t)rw * 64 + ch * 8);
  int4 pv0 = *(const int4*)(vp + (size_t)rw * 2048 + ch * 8);
  int4 cm[2][2], nm[2][2];
#pragma unroll
  for (int qg = 0; qg < 2; ++qg)
#pragma unroll
    for (int bb = 0; bb < 2; ++bb)
      cm[qg][bb] = *(const int4*)(mrow[qg] + bb * 32 + q4 * 8);
  *(int4*)(&Kl[0][sK * 64 + kwc]) = pk0;
  *(int4*)(&Vl[0][rw * 64 + vwc]) = pv0;
  __syncthreads();

  for (int kt = 0; kt < 32; ++kt) {
    const int cur = kt & 1;
    if (kt < 31) {
      const int k0n = (kt + 1) * 64;
      pk0 = *(const int4*)(kp + (size_t)(k0n + rw) * 64 + ch * 8);
      pv0 = *(const int4*)(vp + (size_t)rw * 2048 + k0n + ch * 8);
#pragma unroll
      for (int qg = 0; qg < 2; ++qg)
#pragma unroll
        for (int bb = 0; bb < 2; ++bb)
          nm[qg][bb] = *(const int4*)(mrow[qg] + k0n + bb * 32 + q4 * 8);
    }

#pragma unroll
    for (int bb = 0; bb < 2; ++bb) {
      const int rb = bb * 32;
      const int vc = bb ? rcol1 : rcol0;
      bf16x8 kf00 = *(const bf16x8*)(&Kl[cur][(rb + m16) * 64 + rcol0]);
      bf16x8 kf01 = *(const bf16x8*)(&Kl[cur][(rb + m16) * 64 + rcol1]);
      bf16x8 kf10 = *(const bf16x8*)(&Kl[cur][(rb + 16 + m16) * 64 + rcol0]);
      bf16x8 kf11 = *(const bf16x8*)(&Kl[cur][(rb + 16 + m16) * 64 + rcol1]);
      bf16x8 pa[2];
#pragma unroll
      for (int qg = 0; qg < 2; ++qg) {
        f32x4 sa = (f32x4){0.f, 0.f, 0.f, 0.f};
        f32x4 sb = (f32x4){0.f, 0.f, 0.f, 0.f};
        sa = __builtin_amdgcn_mfma_f32_16x16x32_bf16(kf00, qa[qg][0], sa, 0, 0, 0);
        sa = __builtin_amdgcn_mfma_f32_16x16x32_bf16(kf01, qa[qg][1], sa, 0, 0, 0);
        sb = __builtin_amdgcn_mfma_f32_16x16x32_bf16(kf10, qa[qg][0], sb, 0, 0, 0);
        sb = __builtin_amdgcn_mfma_f32_16x16x32_bf16(kf11, qa[qg][1], sb, 0, 0, 0);
        pa[qg] = pblend(sa, sb, cm[qg][bb]);
        lacc[qg] = __builtin_amdgcn_mfma_f32_16x16x32_bf16(pa[qg], ones, lacc[qg], 0, 0, 0);
      }
#pragma unroll
      for (int e = 0; e < 4; ++e) {
        bf16x8 vf = *(const bf16x8*)(&Vl[cur][(e * 16 + m16) * 64 + vc]);
        oacc[0][e] = __builtin_amdgcn_mfma_f32_16x16x32_bf16(pa[0], vf, oacc[0][e], 0, 0, 0);
        oacc[1][e] = __builtin_amdgcn_mfma_f32_16x16x32_bf16(pa[1], vf, oacc[1][e], 0, 0, 0);
      }
    }

    if (kt < 31) {
      const int nxt = cur ^ 1;
      *(int4*)(&Kl[nxt][sK * 64 + kwc]) = pk0;
      *(int4*)(&Vl[nxt][rw * 64 + vwc]) = pv0;
#pragma unroll
      for (int qg = 0; qg < 2; ++qg)
#pragma unroll
        for (int bb = 0; bb < 2; ++bb) cm[qg][bb] = nm[qg][bb];
      __syncthreads();
    }
  }

  // epilogue: lane's lacc reg r IS the denom for q-row q4*4+r (cols replicated)
#pragma unroll
  for (int qg = 0; qg < 2; ++qg) {
#pragma unroll
    for (int r = 0; r < 4; ++r) {
      float inv = __builtin_amdgcn_rcpf(lacc[qg][r]);
      size_t zr = ((size_t)b * 2048 + qbase + qg * 16 + q4 * 4 + r) * 1024 + h * 64;
#pragma unroll
      for (int e = 0; e < 4; ++e) {
        zb[zr + e * 16 + m16] = f2b(oacc[qg][e][r] * inv);
      }
    }
  }
}

// ---------------------------------------------------------------------------
extern "C" void kernel_launch(void* const* d_in, const int* in_sizes, int n_in,
                              void* d_out, int out_size, void* d_ws, size_t ws_size,
                              hipStream_t stream) {
  const float* x_v = (const float*)d_in[0];
  const float* x_k = (const float*)d_in[1];
  const float* x_q = (const float*)d_in[2];
  const int* mask = (const int*)d_in[3];
  const float* Wq = (const float*)d_in[4];
  const float* bq = (const float*)d_in[5];
  const float* Wk = (const float*)d_in[6];
  const float* bk = (const float*)d_in[7];
  const float* Wv = (const float*)d_in[8];
  const float* bv = (const float*)d_in[9];
  const float* Wo = (const float*)d_in[10];
  const float* bo = (const float*)d_in[11];
  float* out = (float*)d_out;

  char* ws = (char*)d_ws;
  size_t off = 0;
  auto alloc_u16 = [&](size_t n) {
    u16* p = (u16*)(ws + off);
    off += n * sizeof(u16);
    return p;
  };
  u16* wq_t = alloc_u16((size_t)16 * 64 * 1024);  // [h][e][d]
  u16* wk_t = alloc_u16((size_t)16 * 64 * 1024);
  u16* wv_t = alloc_u16((size_t)16 * 64 * 1024);
  u16* wo_t = alloc_u16((size_t)1024 * 1024);     // [n][k]
  u16* qb = alloc_u16((size_t)8192 * 1024);       // [b][h][s][e] (pre-scaled)
  u16* kb = alloc_u16((size_t)8192 * 1024);
  u16* vtb = alloc_u16((size_t)8192 * 1024);      // [b][h][e][s]
  u16* xq16 = alloc_u16((size_t)8192 * 1024);     // reused as zb after q-proj
  u16* xk16 = alloc_u16((size_t)8192 * 1024);     // reused as mask16 (32 MB
  u16* xv16 = alloc_u16((size_t)8192 * 1024);     //   spanning xk16+xv16)
  u16* zb = xq16;
  u16* mask16 = xk16;  // written after qkv_gemm consumed xk16/xv16

  transpose_cvt_all<<<dim3(1024), 256, 0, stream>>>(
      Wq, Wk, Wv, Wo, wq_t, wk_t, wv_t, wo_t);
  const int n4 = 8192 * 1024 / 4;
  cvt_bf16_3<<<dim3(512, 3), 256, 0, stream>>>(
      (const float4*)x_q, (const float4*)x_k, (const float4*)x_v,
      (ushort4*)xq16, (ushort4*)xk16, (ushort4*)xv16, n4);
  qkv_gemm<<<dim3(64, 8, 3), 256, 0, stream>>>(
      xq16, xk16, xv16, wq_t, wk_t, wv_t, bq, bk, bv, qb, kb, vtb);
  expand_mask<<<dim3(2048), 256, 0, stream>>>(
      (const int4*)mask, (ushort4*)mask16, 4 * 2048 * 2048 / 4);
  attn<<<dim3(512), 512, 0, stream>>>(qb, kb, vtb, mask16, zb);
  out_gemm<<<dim3(64, 8), 256, 0, stream>>>(zb, wo_t, bo, out);
}

// Round 9
// 391.228 us; speedup vs baseline: 1.1002x; 1.1002x over previous
//
#include <hip/hip_runtime.h>

typedef unsigned short u16;
typedef unsigned long long u64;
typedef __attribute__((ext_vector_type(8))) short bf16x8;
typedef __attribute__((ext_vector_type(4))) float f32x4;

// B=4, S=2048, D=1024, H=16, HD=64, M=B*S=8192
#define C_SCALE 0.18033688011112043f   // 0.125 * log2(e), folded into Q

__device__ __forceinline__ u16 f2b(float x) {
  union { float f; unsigned u; } c; c.f = x;
  unsigned r = (c.u + 0x7fffu + ((c.u >> 16) & 1u)) >> 16;
  return (u16)r;
}

__device__ __forceinline__ unsigned pk2(float a, float b) {
#if __has_builtin(__builtin_amdgcn_cvt_pk_bf16_f32)
  typedef __attribute__((ext_vector_type(2))) __bf16 b2;
  b2 r = __builtin_amdgcn_cvt_pk_bf16_f32(a, b);
  union { b2 v; unsigned u; } c; c.v = r;
  return c.u;
#else
  union { float f; unsigned u; } x, y;
  x.f = a; y.f = b;
  return ((x.u + 0x8000u) >> 16) | ((y.u + 0x8000u) & 0xffff0000u);
#endif
}

__device__ __forceinline__ void gll16(const u16* g, u16* l) {
  __builtin_amdgcn_global_load_lds(
      (const __attribute__((address_space(1))) void*)g,
      (__attribute__((address_space(3))) void*)l, 16, 0, 0);
}

// exp2 over 8 scores, pack to bf16, blend with 1.0 under halfword select
// mask (0xFFFF keep / 0x0000 -> bf16 1.0). LLVM folds each line to v_bfi.
// Bit-identical to exp2(s*m) with m in {1.0, 0.0}.
__device__ __forceinline__ bf16x8 pblend(f32x4 sa, f32x4 sb, int4 mw) {
  unsigned m0 = (unsigned)mw.x, m1 = (unsigned)mw.y;
  unsigned m2 = (unsigned)mw.z, m3 = (unsigned)mw.w;
  union { unsigned u[4]; bf16x8 v; } pu;
  pu.u[0] = (m0 & pk2(__builtin_amdgcn_exp2f(sa[0]),
                      __builtin_amdgcn_exp2f(sa[1]))) | (~m0 & 0x3f803f80u);
  pu.u[1] = (m1 & pk2(__builtin_amdgcn_exp2f(sa[2]),
                      __builtin_amdgcn_exp2f(sa[3]))) | (~m1 & 0x3f803f80u);
  pu.u[2] = (m2 & pk2(__builtin_amdgcn_exp2f(sb[0]),
                      __builtin_amdgcn_exp2f(sb[1]))) | (~m2 & 0x3f803f80u);
  pu.u[3] = (m3 & pk2(__builtin_amdgcn_exp2f(sb[2]),
                      __builtin_amdgcn_exp2f(sb[3]))) | (~m3 & 0x3f803f80u);
  return pu.v;
}

// ---------------------------------------------------------------------------
// fp32 -> bf16 for all three inputs in one dispatch. Grid (512, 3).
// ---------------------------------------------------------------------------
__global__ __launch_bounds__(256) void cvt_bf16_3(
    const float4* __restrict__ s0, const float4* __restrict__ s1,
    const float4* __restrict__ s2, ushort4* __restrict__ d0,
    ushort4* __restrict__ d1, ushort4* __restrict__ d2, int n4) {
  const int z = blockIdx.y;
  const float4* src = z == 0 ? s0 : z == 1 ? s1 : s2;
  ushort4* dst = z == 0 ? d0 : z == 1 ? d1 : d2;
  int stride = gridDim.x * 256;
  for (int i = blockIdx.x * 256 + threadIdx.x; i < n4; i += stride) {
    float4 v = src[i];
    ushort4 o = { f2b(v.x), f2b(v.y), f2b(v.z), f2b(v.w) };
    dst[i] = o;
  }
}

// ---------------------------------------------------------------------------
// All four weight transposes in one dispatch. Flat grid 1024 blocks.
// ---------------------------------------------------------------------------
__global__ __launch_bounds__(256) void transpose_cvt_all(
    const float* __restrict__ Wq, const float* __restrict__ Wk,
    const float* __restrict__ Wv, const float* __restrict__ Wo,
    u16* __restrict__ wq_t, u16* __restrict__ wk_t,
    u16* __restrict__ wv_t, u16* __restrict__ wo_t) {
  __shared__ u16 tile[64][65];
  const int id = blockIdx.x;
  const int which = id >> 8, sub = id & 255;
  const float* s;
  u16* d;
  int R, C, r0, c0;
  if (which < 3) {
    const float* W = which == 0 ? Wq : which == 1 ? Wk : Wv;
    u16* D = which == 0 ? wq_t : which == 1 ? wk_t : wv_t;
    int h = sub >> 4, rt = sub & 15;
    s = W + (size_t)h * 1024 * 64;
    d = D + (size_t)h * 64 * 1024;
    R = 1024; C = 64; r0 = rt * 64; c0 = 0;
  } else {
    s = Wo; d = wo_t;
    R = 1024; C = 1024; r0 = ((sub >> 4) & 15) * 64; c0 = (sub & 15) * 64;
  }
  const int t = threadIdx.x;
#pragma unroll
  for (int rep = 0; rep < 16; ++rep) {
    int idx = rep * 256 + t;
    int i = idx >> 6, j = idx & 63;
    tile[j][i] = f2b(s[(size_t)(r0 + i) * C + c0 + j]);
  }
  __syncthreads();
#pragma unroll
  for (int rep = 0; rep < 16; ++rep) {
    int idx = rep * 256 + t;
    int jj = idx >> 6, ii = idx & 63;
    d[(size_t)(c0 + jj) * R + r0 + ii] = tile[jj][ii];
  }
}

// ---------------------------------------------------------------------------
// Expand mask int32 [B,S,S] -> u16 halfword SELECT masks: 0xFFFF where
// mask!=0 (keep exp2(s)), 0x0000 where mask==0 (inject bf16 1.0 in attn).
// ---------------------------------------------------------------------------
__global__ __launch_bounds__(256) void expand_mask(
    const int4* __restrict__ m, ushort4* __restrict__ mb, int n4) {
  int stride = gridDim.x * 256;
  for (int i = blockIdx.x * 256 + threadIdx.x; i < n4; i += stride) {
    int4 v = m[i];
    ushort4 o = { (u16)(v.x ? 0xFFFF : 0), (u16)(v.y ? 0xFFFF : 0),
                  (u16)(v.z ? 0xFFFF : 0), (u16)(v.w ? 0xFFFF : 0) };
    mb[i] = o;
  }
}

// ---------------------------------------------------------------------------
// GEMM core: 128x128 tile, BK=64, global_load_lds width-16 staging.
// ---------------------------------------------------------------------------
__device__ __forceinline__ void gemm_core(
    const u16* __restrict__ A, const u16* __restrict__ W,
    u16* Asm, u16* Bsm, int s0, int n0, int wv, int lane,
    int m16, int q4, f32x4 acc[4][4]) {
  const int rsub = lane >> 3, csub = lane & 7;
  const int wr = (wv & 1) * 64, wc = (wv >> 1) * 64;
  for (int k0 = 0; k0 < 1024; k0 += 64) {
    __syncthreads();
#pragma unroll
    for (int i = 0; i < 4; ++i) {
      int chunk = wv * 4 + i;
      gll16(A + (size_t)(s0 + chunk * 8 + rsub) * 1024 + k0 + csub * 8,
            Asm + chunk * 512 + lane * 8);
      gll16(W + (size_t)(n0 + chunk * 8 + rsub) * 1024 + k0 + csub * 8,
            Bsm + chunk * 512 + lane * 8);
    }
    __syncthreads();
#pragma unroll
    for (int ks = 0; ks < 2; ++ks) {
      bf16x8 af[4], bfr[4];
#pragma unroll
      for (int i = 0; i < 4; ++i)
        af[i] = *(const bf16x8*)(Asm + (wr + i * 16 + m16) * 64 + ks * 32 + q4 * 8);
#pragma unroll
      for (int j = 0; j < 4; ++j)
        bfr[j] = *(const bf16x8*)(Bsm + (wc + j * 16 + m16) * 64 + ks * 32 + q4 * 8);
#pragma unroll
      for (int i = 0; i < 4; ++i)
#pragma unroll
        for (int j = 0; j < 4; ++j)
          acc[i][j] = __builtin_amdgcn_mfma_f32_16x16x32_bf16(af[i], bfr[j], acc[i][j], 0, 0, 0);
    }
  }
}

// ---------------------------------------------------------------------------
// Merged QKV projection: grid (64, 8, 3). z=0: Q (scaled), z=1: K, z=2: V
// (transposed epilogue -> vt[b][h][e][2048]). (256,3): 3 blocks/CU.
// Round-9: Q/K epilogue repacks through LDS with stride 136 (272 B rows =
// 16-B aligned for ds_read_b128 -- the r8 container crash was stride 132's
// 264 B rows putting odd rows at 8-mod-16 byte offsets). 8 coalesced int4
// stores/thread instead of 64 scattered scalar u16 stores.
// ---------------------------------------------------------------------------
__global__ __launch_bounds__(256, 3) void qkv_gemm(
    const u16* __restrict__ xq, const u16* __restrict__ xk,
    const u16* __restrict__ xv, const u16* __restrict__ wq,
    const u16* __restrict__ wk, const u16* __restrict__ wv_,
    const float* __restrict__ bq, const float* __restrict__ bk,
    const float* __restrict__ bv, u16* __restrict__ qb,
    u16* __restrict__ kb, u16* __restrict__ vtb) {
  __shared__ u16 S[17408];
  u16* Asm = S;
  u16* Bsm = S + 8192;
  const int z = blockIdx.z;
  const u16* A = z == 0 ? xq : z == 1 ? xk : xv;
  const u16* W = z == 0 ? wq : z == 1 ? wk : wv_;
  const float* bias = z == 0 ? bq : z == 1 ? bk : bv;
  const int s0 = blockIdx.x * 128, n0 = blockIdx.y * 128;
  const int t = threadIdx.x, wvi = t >> 6, lane = t & 63;
  const int m16 = lane & 15, q4 = lane >> 4;
  const int wr = (wvi & 1) * 64, wc = (wvi >> 1) * 64;
  f32x4 acc[4][4];
#pragma unroll
  for (int i = 0; i < 4; ++i)
#pragma unroll
    for (int j = 0; j < 4; ++j) acc[i][j] = (f32x4){0.f, 0.f, 0.f, 0.f};

  gemm_core(A, W, Asm, Bsm, s0, n0, wvi, lane, m16, q4, acc);

  if (z < 2) {
    // Q/K: repack [sloc][nl] through LDS (stride 136, 16-B aligned rows),
    // write int4 chunks to out[b][h][s][e] (e contiguous).
    u16* out = z == 0 ? qb : kb;
    const float scale = z == 0 ? C_SCALE : 1.0f;
    __syncthreads();
#pragma unroll
    for (int j = 0; j < 4; ++j) {
      int nl = wc + j * 16 + m16;
      float bval = bias[n0 + nl];
#pragma unroll
      for (int i = 0; i < 4; ++i)
#pragma unroll
        for (int r = 0; r < 4; ++r)
          S[(wr + i * 16 + q4 * 4 + r) * 136 + nl] =
              f2b((acc[i][j][r] + bval) * scale);
    }
    __syncthreads();
    const int bi = s0 >> 11, sl0 = s0 & 2047;
#pragma unroll
    for (int rep = 0; rep < 8; ++rep) {  // 128x128 tile = 2048 int4 units
      int u = rep * 256 + t;
      int rr = u >> 4, cc = (u & 15) * 8;
      int h = (n0 + cc) >> 6, e = cc & 63;
      *(int4*)(out + ((size_t)(bi * 16 + h) * 2048 + sl0 + rr) * 64 + e) =
          *(const int4*)(S + rr * 136 + cc);
    }
  } else {
    // V: transpose through LDS (stride 136), write vt[b][h][e][2048]
    __syncthreads();
#pragma unroll
    for (int j = 0; j < 4; ++j) {
      int nl = wc + j * 16 + m16;
      float bval = bias[n0 + nl];
#pragma unroll
      for (int i = 0; i < 4; ++i)
#pragma unroll
        for (int r = 0; r < 4; ++r)
          S[nl * 136 + wr + i * 16 + q4 * 4 + r] = f2b(acc[i][j][r] + bval);
    }
    __syncthreads();
    const int bi = s0 >> 11, sl0 = s0 & 2047;
#pragma unroll
    for (int rep = 0; rep < 8; ++rep) {  // 128x128 tile = 2048 int4 units
      int u = rep * 256 + t;
      int rr = u >> 4, cc = (u & 15) * 8;
      int n = n0 + rr, h = n >> 6, e = n & 63;
      *(int4*)(vtb + ((size_t)(bi * 16 + h) * 64 + e) * 2048 + sl0 + cc) =
          *(const int4*)(S + rr * 136 + cc);
    }
  }
}

// ---------------------------------------------------------------------------
// Output GEMM: fp32 out [s][1024]. Grid (64, 8).
// ---------------------------------------------------------------------------
__global__ __launch_bounds__(256, 2) void out_gemm(
    const u16* __restrict__ Z, const u16* __restrict__ Wot,
    const float* __restrict__ bo, float* __restrict__ out) {
  __shared__ u16 S[17408];
  u16* Asm = S;
  u16* Bsm = S + 8192;
  const int s0 = blockIdx.x * 128, n0 = blockIdx.y * 128;
  const int t = threadIdx.x, wvi = t >> 6, lane = t & 63;
  const int m16 = lane & 15, q4 = lane >> 4;
  const int wr = (wvi & 1) * 64, wc = (wvi >> 1) * 64;
  f32x4 acc[4][4];
#pragma unroll
  for (int i = 0; i < 4; ++i)
#pragma unroll
    for (int j = 0; j < 4; ++j) acc[i][j] = (f32x4){0.f, 0.f, 0.f, 0.f};

  gemm_core(Z, Wot, Asm, Bsm, s0, n0, wvi, lane, m16, q4, acc);

#pragma unroll
  for (int j = 0; j < 4; ++j) {
    int n = n0 + wc + j * 16 + m16;
    float bval = bo[n];
#pragma unroll
    for (int i = 0; i < 4; ++i)
#pragma unroll
      for (int r = 0; r < 4; ++r) {
        int s = s0 + wr + i * 16 + q4 * 4 + r;
        out[(size_t)s * 1024 + n] = acc[i][j][r] + bval;
      }
  }
}

// ---------------------------------------------------------------------------
// Flash attention, no-max softmax.
// Masking: mk holds halfword select masks; pa = BFI(m, pk2(exp2(s)), 1.0).
// Round-9 attn = round-8 attn unchanged (the r8 crash was qkv's stride-132
// misalignment, not attn): round-4 structure + BFI with the register bill
// paid:
//  - nm MERGED into cm: next tile's masks load into the SAME registers
//    AFTER last use (WAR ordering; zero copies; -16 VGPR vs r4). Prefetch
//    distance preserved (loads issue one barrier before use).
//  - BFI blend (+~4 VGPR): net -12 vs r4 -> fits the (512,4) 64-VGPR cap
//    (r7: BFI+nm = 4 over -> 16 MB spill; r6: uncapped = 68 VGPR -> 1
//    block/CU. This config is the only one that can hold both wins.)
//  - Everything else identical to r4: 8-wave/512-thr, swizzled LDS,
//    K/V reg prefetch, no setprio, rcp epilogue.
// ---------------------------------------------------------------------------
__global__ __launch_bounds__(512, 4) void attn(
    const u16* __restrict__ qb, const u16* __restrict__ kb,
    const u16* __restrict__ vt, const u16* __restrict__ mk,
    u16* __restrict__ zb) {
  __shared__ u16 Kl[2][4096];  // permuted-key rows, [64][64] swizzled
  __shared__ u16 Vl[2][4096];  // [e][key] natural, swizzled
  const int id = blockIdx.x;
  const int qi = id >> 6;      // 0..7 (256-q tiles)
  const int bh = id & 63;
  const int b = bh >> 4, h = bh & 15;
  const int t = threadIdx.x, w = t >> 6, lane = t & 63;  // w 0..7
  const int m16 = lane & 15, q4 = lane >> 4;
  const size_t bho = (size_t)bh * 2048;
  const u16* qp = qb + bho * 64;
  const u16* kp = kb + bho * 64;
  const u16* vp = vt + bho * 64;  // [e][2048]
  const int qbase = qi * 256 + w * 32;

  bf16x8 qa[2][2];
#pragma unroll
  for (int qg = 0; qg < 2; ++qg)
#pragma unroll
    for (int ks = 0; ks < 2; ++ks)
      qa[qg][ks] = *(const bf16x8*)(qp + (size_t)(qbase + qg * 16 + m16) * 64 + ks * 32 + q4 * 8);

  f32x4 oacc[2][4], lacc[2];
#pragma unroll
  for (int qg = 0; qg < 2; ++qg) {
    lacc[qg] = (f32x4){0.f, 0.f, 0.f, 0.f};
#pragma unroll
    for (int g = 0; g < 4; ++g) oacc[qg][g] = (f32x4){0.f, 0.f, 0.f, 0.f};
  }
  bf16x8 ones;
#pragma unroll
  for (int j = 0; j < 8; ++j) ones[j] = (short)0x3f80;

  // select-mask rows for this lane's two q rows; keys contiguous
  const u16* mrow0 = mk + ((size_t)b * 2048 + qbase + m16) * 2048;
  const u16* mrow1 = mrow0 + (size_t)16 * 2048;

  const int ch = t & 7, rw = t >> 3;  // rw in 0..63
  const int r5 = rw & 31;
  const int sK = (rw & 32) + (((r5 >> 2) & 1) * 16) + (((r5 >> 3) & 3) * 4) + (r5 & 3);

  // XOR-swizzle terms (u16 units; 8 u16 = 16 B slot)
  const int kwc = (ch ^ (sK & 7)) * 8;       // K write col
  const int vwc = (ch ^ (rw & 7)) * 8;       // V write col (row = e = rw)
  const int sw = (m16 & 7) * 8;              // read-side XOR (row&7 == m16&7)
  const int rcol0 = (q4 * 8) ^ sw;           // ks=0 / bb=0 read col
  const int rcol1 = (32 + q4 * 8) ^ sw;      // ks=1 / bb=1 read col

  // prefetch tile 0 + mask tile 0
  int4 pk0 = *(const int4*)(kp + (size_t)rw * 64 + ch * 8);
  int4 pv0 = *(const int4*)(vp + (size_t)rw * 2048 + ch * 8);
  int4 cm00 = *(const int4*)(mrow0 + q4 * 8);
  int4 cm01 = *(const int4*)(mrow0 + 32 + q4 * 8);
  int4 cm10 = *(const int4*)(mrow1 + q4 * 8);
  int4 cm11 = *(const int4*)(mrow1 + 32 + q4 * 8);
  *(int4*)(&Kl[0][sK * 64 + kwc]) = pk0;
  *(int4*)(&Vl[0][rw * 64 + vwc]) = pv0;
  __syncthreads();

  for (int kt = 0; kt < 32; ++kt) {
    const int cur = kt & 1;
    if (kt < 31) {
      const int k0n = (kt + 1) * 64;
      pk0 = *(const int4*)(kp + (size_t)(k0n + rw) * 64 + ch * 8);
      pv0 = *(const int4*)(vp + (size_t)rw * 2048 + k0n + ch * 8);
    }

#pragma unroll
    for (int bb = 0; bb < 2; ++bb) {
      const int rb = bb * 32;
      const int vc = bb ? rcol1 : rcol0;
      bf16x8 kf00 = *(const bf16x8*)(&Kl[cur][(rb + m16) * 64 + rcol0]);
      bf16x8 kf01 = *(const bf16x8*)(&Kl[cur][(rb + m16) * 64 + rcol1]);
      bf16x8 kf10 = *(const bf16x8*)(&Kl[cur][(rb + 16 + m16) * 64 + rcol0]);
      bf16x8 kf11 = *(const bf16x8*)(&Kl[cur][(rb + 16 + m16) * 64 + rcol1]);
      bf16x8 pa[2];
#pragma unroll
      for (int qg = 0; qg < 2; ++qg) {
        f32x4 sa = (f32x4){0.f, 0.f, 0.f, 0.f};
        f32x4 sb = (f32x4){0.f, 0.f, 0.f, 0.f};
        sa = __builtin_amdgcn_mfma_f32_16x16x32_bf16(kf00, qa[qg][0], sa, 0, 0, 0);
        sa = __builtin_amdgcn_mfma_f32_16x16x32_bf16(kf01, qa[qg][1], sa, 0, 0, 0);
        sb = __builtin_amdgcn_mfma_f32_16x16x32_bf16(kf10, qa[qg][0], sb, 0, 0, 0);
        sb = __builtin_amdgcn_mfma_f32_16x16x32_bf16(kf11, qa[qg][1], sb, 0, 0, 0);
        const int4 mw = qg == 0 ? (bb ? cm01 : cm00) : (bb ? cm11 : cm10);
        pa[qg] = pblend(sa, sb, mw);
        lacc[qg] = __builtin_amdgcn_mfma_f32_16x16x32_bf16(pa[qg], ones, lacc[qg], 0, 0, 0);
      }
#pragma unroll
      for (int e = 0; e < 4; ++e) {
        bf16x8 vf = *(const bf16x8*)(&Vl[cur][(e * 16 + m16) * 64 + vc]);
        oacc[0][e] = __builtin_amdgcn_mfma_f32_16x16x32_bf16(pa[0], vf, oacc[0][e], 0, 0, 0);
        oacc[1][e] = __builtin_amdgcn_mfma_f32_16x16x32_bf16(pa[1], vf, oacc[1][e], 0, 0, 0);
      }
    }

    if (kt < 31) {
      const int nxt = cur ^ 1;
      const int k0n = (kt + 1) * 64;
      // reload next tile's masks into the SAME regs (after last use above)
      cm00 = *(const int4*)(mrow0 + k0n + q4 * 8);
      cm01 = *(const int4*)(mrow0 + k0n + 32 + q4 * 8);
      cm10 = *(const int4*)(mrow1 + k0n + q4 * 8);
      cm11 = *(const int4*)(mrow1 + k0n + 32 + q4 * 8);
      *(int4*)(&Kl[nxt][sK * 64 + kwc]) = pk0;
      *(int4*)(&Vl[nxt][rw * 64 + vwc]) = pv0;
      __syncthreads();
    }
  }

  // epilogue: lane's lacc reg r IS the denom for q-row q4*4+r (cols replicated)
#pragma unroll
  for (int qg = 0; qg < 2; ++qg) {
#pragma unroll
    for (int r = 0; r < 4; ++r) {
      float inv = __builtin_amdgcn_rcpf(lacc[qg][r]);
      size_t zr = ((size_t)b * 2048 + qbase + qg * 16 + q4 * 4 + r) * 1024 + h * 64;
#pragma unroll
      for (int e = 0; e < 4; ++e) {
        zb[zr + e * 16 + m16] = f2b(oacc[qg][e][r] * inv);
      }
    }
  }
}

// ---------------------------------------------------------------------------
extern "C" void kernel_launch(void* const* d_in, const int* in_sizes, int n_in,
                              void* d_out, int out_size, void* d_ws, size_t ws_size,
                              hipStream_t stream) {
  const float* x_v = (const float*)d_in[0];
  const float* x_k = (const float*)d_in[1];
  const float* x_q = (const float*)d_in[2];
  const int* mask = (const int*)d_in[3];
  const float* Wq = (const float*)d_in[4];
  const float* bq = (const float*)d_in[5];
  const float* Wk = (const float*)d_in[6];
  const float* bk = (const float*)d_in[7];
  const float* Wv = (const float*)d_in[8];
  const float* bv = (const float*)d_in[9];
  const float* Wo = (const float*)d_in[10];
  const float* bo = (const float*)d_in[11];
  float* out = (float*)d_out;

  char* ws = (char*)d_ws;
  size_t off = 0;
  auto alloc_u16 = [&](size_t n) {
    u16* p = (u16*)(ws + off);
    off += n * sizeof(u16);
    return p;
  };
  u16* wq_t = alloc_u16((size_t)16 * 64 * 1024);  // [h][e][d]
  u16* wk_t = alloc_u16((size_t)16 * 64 * 1024);
  u16* wv_t = alloc_u16((size_t)16 * 64 * 1024);
  u16* wo_t = alloc_u16((size_t)1024 * 1024);     // [n][k]
  u16* qb = alloc_u16((size_t)8192 * 1024);       // [b][h][s][e] (pre-scaled)
  u16* kb = alloc_u16((size_t)8192 * 1024);
  u16* vtb = alloc_u16((size_t)8192 * 1024);      // [b][h][e][s]
  u16* xq16 = alloc_u16((size_t)8192 * 1024);     // reused as zb after q-proj
  u16* xk16 = alloc_u16((size_t)8192 * 1024);     // reused as mask16 (32 MB
  u16* xv16 = alloc_u16((size_t)8192 * 1024);     //   spanning xk16+xv16)
  u16* zb = xq16;
  u16* mask16 = xk16;  // written after qkv_gemm consumed xk16/xv16

  transpose_cvt_all<<<dim3(1024), 256, 0, stream>>>(
      Wq, Wk, Wv, Wo, wq_t, wk_t, wv_t, wo_t);
  const int n4 = 8192 * 1024 / 4;
  cvt_bf16_3<<<dim3(512, 3), 256, 0, stream>>>(
      (const float4*)x_q, (const float4*)x_k, (const float4*)x_v,
      (ushort4*)xq16, (ushort4*)xk16, (ushort4*)xv16, n4);
  qkv_gemm<<<dim3(64, 8, 3), 256, 0, stream>>>(
      xq16, xk16, xv16, wq_t, wk_t, wv_t, bq, bk, bv, qb, kb, vtb);
  expand_mask<<<dim3(2048), 256, 0, stream>>>(
      (const int4*)mask, (ushort4*)mask16, 4 * 2048 * 2048 / 4);
  attn<<<dim3(512), 512, 0, stream>>>(qb, kb, vtb, mask16, zb);
  out_gemm<<<dim3(64, 8), 256, 0, stream>>>(zb, wo_t, bo, out);
}